// Round 4
// baseline (1248.777 us; speedup 1.0000x reference)
//
#include <hip/hip_runtime.h>
#include <hip/hip_bf16.h>

#define D_MODEL 4096
#define D_FF    11008
#define NTOK    4096   // 2 * 2048 tokens

typedef unsigned int u32;
typedef unsigned short u16;
using f32x4   = __attribute__((ext_vector_type(4))) float;
using bf16x8  = __attribute__((ext_vector_type(8))) short;
using ushort8 = __attribute__((ext_vector_type(8))) unsigned short;
using int4v   = __attribute__((ext_vector_type(4))) int;
using float4v = __attribute__((ext_vector_type(4))) float;

__device__ __forceinline__ u16 bf16_rn(float f) {
    u32 u = __builtin_bit_cast(u32, f);
    u += 0x7FFFu + ((u >> 16) & 1u);
    return (u16)(u >> 16);
}
__device__ __forceinline__ u16 bf16_from_int(int v) {
    float f = (float)v;   // exact for |v| <= 127
    return (u16)(__builtin_bit_cast(u32, f) >> 16);
}
__device__ __forceinline__ float bf16_to_f(u16 b) {
    u32 u = (u32)b << 16;
    return __builtin_bit_cast(float, u);
}
__device__ __forceinline__ void gload16(const void* g, void* l) {
    __builtin_amdgcn_global_load_lds(
        (const __attribute__((address_space(1))) u32*)g,
        (__attribute__((address_space(3))) u32*)l, 16, 0, 0);
}

// ---------------- x fp32 -> bf16 ----------------
__global__ void k_cvt_x(const float* __restrict__ x, u16* __restrict__ xb) {
    int i = (blockIdx.x * 256 + threadIdx.x) * 8;
    float4v a = *(const float4v*)(x + i);
    float4v b = *(const float4v*)(x + i + 4);
    ushort8 o;
    o[0] = bf16_rn(a[0]); o[1] = bf16_rn(a[1]); o[2] = bf16_rn(a[2]); o[3] = bf16_rn(a[3]);
    o[4] = bf16_rn(b[0]); o[5] = bf16_rn(b[1]); o[6] = bf16_rn(b[2]); o[7] = bf16_rn(b[3]);
    *(ushort8*)(xb + i) = o;
}

// ---------------- weight int32 -> bf16 ----------------
__global__ void k_cvt_w(const int* __restrict__ w, u16* __restrict__ wb, int n) {
    int i = (blockIdx.x * 256 + threadIdx.x) * 8;
    if (i >= n) return;
    int4v a = *(const int4v*)(w + i);
    int4v b = *(const int4v*)(w + i + 4);
    ushort8 o;
    o[0] = bf16_from_int(a[0]); o[1] = bf16_from_int(a[1]);
    o[2] = bf16_from_int(a[2]); o[3] = bf16_from_int(a[3]);
    o[4] = bf16_from_int(b[0]); o[5] = bf16_from_int(b[1]);
    o[6] = bf16_from_int(b[2]); o[7] = bf16_from_int(b[3]);
    *(ushort8*)(wb + i) = o;
}

// =====================================================================
// 256x256 GEMM, 4 quadrant-phases/K-tile, fragment reads PREFETCHED one
// phase ahead with counted lgkmcnt so LDS reads overlap MFMA.
// C = A[M][K] * (B[N][K])^T (bf16, K-major). 8 waves (2M x 4N), BK=64,
// double-buffered 128 KiB LDS, XOR-granule swizzle, vmcnt(6) at P3.
// EPI: 0 = obf = bf16(acc*scale)                      (gate)
//      1 = obf = bf16(silu(g)*acc*scale), g from obf  (up + fuse)
//      2 = of32 = acc*scale                           (down)
// =====================================================================

#define DSR(dst, addr, IMM)                                                   \
  asm volatile("ds_read_b128 %0, %1 offset:%c2"                               \
               : "=v"(dst) : "v"(addr), "i"(IMM))

// A-half byte layout: buf*65536 + half*16384, row stride 128B, m-stride 2048B
#define READA(AA, BUF, MH) {                                                  \
  DSR(AA[0][0], adA##BUF##g0, (MH)*16384 + 0);                                \
  DSR(AA[0][1], adA##BUF##g1, (MH)*16384 + 0);                                \
  DSR(AA[1][0], adA##BUF##g0, (MH)*16384 + 2048);                             \
  DSR(AA[1][1], adA##BUF##g1, (MH)*16384 + 2048);                             \
  DSR(AA[2][0], adA##BUF##g0, (MH)*16384 + 4096);                             \
  DSR(AA[2][1], adA##BUF##g1, (MH)*16384 + 4096);                             \
  DSR(AA[3][0], adA##BUF##g0, (MH)*16384 + 6144);                             \
  DSR(AA[3][1], adA##BUF##g1, (MH)*16384 + 6144); }

#define READB(BB, BUF, NH) {                                                  \
  DSR(BB[0][0], adB##BUF##g0, (NH)*16384 + 0);                                \
  DSR(BB[0][1], adB##BUF##g1, (NH)*16384 + 0);                                \
  DSR(BB[1][0], adB##BUF##g0, (NH)*16384 + 2048);                             \
  DSR(BB[1][1], adB##BUF##g1, (NH)*16384 + 2048); }

#define MFMA16(MH, NH, AA, BB)                                                \
  _Pragma("unroll") for (int mm = 0; mm < 4; ++mm)                            \
  _Pragma("unroll") for (int nn = 0; nn < 2; ++nn)                            \
  _Pragma("unroll") for (int kk = 0; kk < 2; ++kk)                            \
    acc[(MH)*4+mm][(NH)*2+nn] = __builtin_amdgcn_mfma_f32_16x16x32_bf16(      \
        AA[mm][kk], BB[nn][kk], acc[(MH)*4+mm][(NH)*2+nn], 0, 0, 0);

// LDS element offsets for staging (ushort units)
#define REGA(BUF, H) ((BUF)*32768 + (H)*8192)
#define REGB(BUF, H) ((BUF)*32768 + 16384 + (H)*8192)

#define STAGE_A(BUF, MH, K0) {                                                \
  const u16* _s = A + a_sbase + (size_t)(MH)*128*K + (K0);                    \
  gload16(_s,                &lds[REGA(BUF, MH) + wave*512]);                 \
  gload16(_s + (size_t)64*K, &lds[REGA(BUF, MH) + (8+wave)*512]); }

#define STAGE_B(BUF, NH, K0) {                                                \
  const u16* _s = B + b_sbase + (size_t)(NH)*128*K + (K0);                    \
  gload16(_s,                &lds[REGB(BUF, NH) + wave*512]);                 \
  gload16(_s + (size_t)64*K, &lds[REGB(BUF, NH) + (8+wave)*512]); }

#define BAR   __builtin_amdgcn_s_barrier()
#define SB0   __builtin_amdgcn_sched_barrier(0)
#define PRIO1 __builtin_amdgcn_s_setprio(1)
#define PRIO0 __builtin_amdgcn_s_setprio(0)
#define VMC(N)  asm volatile("s_waitcnt vmcnt(" #N ")" ::: "memory")
#define LGKM(N) asm volatile("s_waitcnt lgkmcnt(" #N ")" ::: "memory")

#define TILE(CUR, NXT, T) {                                                   \
  /* P1: Q1(a0,b0); front: issue b1 reads (4) */                              \
  READB(b1, CUR, 1);                                                          \
  BAR; LGKM(4); SB0; PRIO1; MFMA16(0, 0, a0, b0); PRIO0; BAR;                 \
  /* P2: Q2(a0,b1); front: issue a1 reads (8); stage A0,B0 (t+2) */           \
  READA(a1, CUR, 1);                                                          \
  if ((T)+2 < nt) { STAGE_A(CUR, 0, ((T)+2) << 6);                            \
                    STAGE_B(CUR, 0, ((T)+2) << 6); }                          \
  BAR; LGKM(8); SB0; PRIO1; MFMA16(0, 1, a0, b1); PRIO0; BAR;                 \
  /* P3: Q3(a1,b1); stage B1 (t+2); vmcnt gates entire NXT buffer */          \
  if ((T)+2 < nt) STAGE_B(CUR, 1, ((T)+2) << 6);                              \
  BAR; LGKM(0); SB0; PRIO1; MFMA16(1, 1, a1, b1); PRIO0;                      \
  if ((T)+2 < nt) { VMC(6); } else { VMC(0); }                                \
  BAR;                                                                        \
  /* P4: Q4(a1,b0); front: prefetch a0' (a0 dead since Q2); stage A1;  */     \
  /*     tail: prefetch b0' AFTER MFMA (b0 live in Q4) + SB0 pin       */     \
  if ((T)+1 < nt) READA(a0, NXT, 0);                                          \
  if ((T)+2 < nt) STAGE_A(CUR, 1, ((T)+2) << 6);                              \
  BAR; SB0; PRIO1; MFMA16(1, 0, a1, b0); PRIO0; SB0;                          \
  if ((T)+1 < nt) READB(b0, NXT, 0);                                          \
  BAR; }

template<int EPI>
__global__ __launch_bounds__(512, 2) void k_gemm256(
    const u16* __restrict__ A, const u16* __restrict__ B,
    const float* __restrict__ scale,
    u16* __restrict__ obf, float* __restrict__ of32,
    int K, int NBN, int ldc)
{
    __shared__ __align__(16) u16 lds[65536];   // 128 KiB

    const int tid  = threadIdx.x;
    const int lane = tid & 63;
    const int wave = tid >> 6;          // 0..7
    const int wm   = wave >> 2;         // 0..1
    const int wn   = wave & 3;          // 0..3

    // XCD-aware bijective swizzle (m204)
    const int nwg  = 16 * NBN;
    const int orig = blockIdx.x;
    const int qq   = nwg >> 3, rr = nwg & 7;
    const int xcd  = orig & 7;
    const int swz  = (xcd < rr ? xcd*(qq+1) : rr*(qq+1) + (xcd-rr)*qq) + (orig >> 3);
    const int bm   = swz & 15;          // M blocks = 4096/256 = 16
    const int bn   = swz >> 4;

    // fragment-read per-thread constants (byte offsets)
    const int r    = lane & 15;
    const int sQ   = lane >> 4;         // 0..3
    const int x7   = r & 7;
    const int g0B  = ((sQ ^ x7) * 8) * 2;         // kk=0 granule, bytes
    const int g1B  = (((4 | sQ) ^ x7) * 8) * 2;   // kk=1 granule, bytes
    const int aoffB = (wm*64 + r) * 128;
    const int boffB = (wn*32 + r) * 128;

    const u32 lbase = (u32)(uintptr_t)(__attribute__((address_space(3))) u16*)&lds[0];
    const u32 adA0g0 = lbase + aoffB + g0B;
    const u32 adA0g1 = lbase + aoffB + g1B;
    const u32 adA1g0 = adA0g0 + 65536;
    const u32 adA1g1 = adA0g1 + 65536;
    const u32 adB0g0 = lbase + 32768 + boffB + g0B;
    const u32 adB0g1 = lbase + 32768 + boffB + g1B;
    const u32 adB1g0 = adB0g0 + 65536;
    const u32 adB1g1 = adB0g1 + 65536;

    // stage per-thread constants (inverse swizzle on the global source)
    const int lrow = lane >> 3;                       // 0..7
    const int goff = ((lane & 7) ^ lrow) * 8;         // elems within 64-col row
    const size_t a_sbase = (size_t)(bm*256 + wave*8 + lrow) * K + goff;
    const size_t b_sbase = (size_t)(bn*256 + wave*8 + lrow) * K + goff;

    f32x4 acc[8][4];
#pragma unroll
    for (int m = 0; m < 8; ++m)
#pragma unroll
        for (int n = 0; n < 4; ++n) acc[m][n] = (f32x4){0.f, 0.f, 0.f, 0.f};

    const int nt = K >> 6;              // K/64: 64 (d=4096) or 172 (d=11008), even

    // ---- prologue: fully stage tile0 -> buf0, tile1 -> buf1 (16 gloads)
    STAGE_A(0, 0, 0); STAGE_B(0, 0, 0); STAGE_B(0, 1, 0); STAGE_A(0, 1, 0);
    STAGE_A(1, 0, 64); STAGE_B(1, 0, 64); STAGE_B(1, 1, 64); STAGE_A(1, 1, 64);
    VMC(8);                              // own tile0 contributions complete
    BAR;                                 // all waves' tile0 contributions done

    bf16x8 a0[4][2], a1[4][2], b0[2][2], b1[2][2];
    READA(a0, 0, 0);                     // G1(t=0): 12 reads of buf0
    READB(b0, 0, 0);

    for (int t = 0; t < nt; t += 2) {
        TILE(0, 1, t);
        TILE(1, 0, t + 1);
    }

    // ---- epilogue
#pragma unroll
    for (int n = 0; n < 4; ++n) {
        const int col = bn*256 + (n>>1)*128 + wn*32 + (n&1)*16 + r;
        const float sc = scale[col];
#pragma unroll
        for (int m = 0; m < 8; ++m) {
            const int row = bm*256 + (m>>2)*128 + wm*64 + (m&3)*16 + sQ*4;
#pragma unroll
            for (int q = 0; q < 4; ++q) {
                const float v = acc[m][n][q] * sc;
                const size_t idx = (size_t)(row + q) * ldc + col;
                if constexpr (EPI == 0) {
                    obf[idx] = bf16_rn(v);
                } else if constexpr (EPI == 1) {
                    const float g = bf16_to_f(obf[idx]);
                    const float s2 = g / (1.0f + __expf(-g));
                    obf[idx] = bf16_rn(s2 * v);
                } else {
                    of32[idx] = v;
                }
            }
        }
    }
}

extern "C" void kernel_launch(void* const* d_in, const int* in_sizes, int n_in,
                              void* d_out, int out_size, void* d_ws, size_t ws_size,
                              hipStream_t stream) {
    const float* x  = (const float*)d_in[0];
    const int*   gw = (const int*)d_in[1];
    const float* gs = (const float*)d_in[2];
    const int*   uw = (const int*)d_in[3];
    const float* us = (const float*)d_in[4];
    const int*   dw = (const int*)d_in[5];
    const float* ds = (const float*)d_in[6];
    float* out = (float*)d_out;

    const size_t XB = (size_t)NTOK * D_MODEL * 2;   // 33.5 MB  x bf16
    const size_t WB = (size_t)D_FF * D_MODEL * 2;   // 90.2 MB  weight bf16
    const size_t HB = WB;                           // 90.2 MB  g/h bf16
    if (ws_size < XB + WB + HB) return;             // loud failure (poisoned out)

    char* ws = (char*)d_ws;
    u16* xb   = (u16*)ws;
    u16* wb   = (u16*)(ws + XB);
    u16* gbuf = (u16*)(ws + XB + WB);

    const int wn_elems = D_FF * D_MODEL;            // 45,088,768
    const int wgrid = wn_elems / (8 * 256);

    k_cvt_x<<<(NTOK * D_MODEL) / (8 * 256), 256, 0, stream>>>(x, xb);

    // gate: g = bf16( (xb . gw^T) * gs )
    k_cvt_w<<<wgrid, 256, 0, stream>>>(gw, wb, wn_elems);
    k_gemm256<0><<<16 * (D_FF / 256), 512, 0, stream>>>(
        xb, wb, gs, gbuf, nullptr, D_MODEL, D_FF / 256, D_FF);

    // up + fuse: h = bf16( silu(g) * (xb . uw^T) * us )   (in-place into gbuf)
    k_cvt_w<<<wgrid, 256, 0, stream>>>(uw, wb, wn_elems);
    k_gemm256<1><<<16 * (D_FF / 256), 512, 0, stream>>>(
        xb, wb, us, gbuf, nullptr, D_MODEL, D_FF / 256, D_FF);

    // down: out = (h . dw^T) * ds   (fp32)
    k_cvt_w<<<wgrid, 256, 0, stream>>>(dw, wb, wn_elems);
    k_gemm256<2><<<16 * (D_MODEL / 256), 512, 0, stream>>>(
        gbuf, wb, ds, nullptr, out, D_FF, D_MODEL / 256, D_MODEL);
}